// Round 5
// baseline (285.060 us; speedup 1.0000x reference)
//
#include <hip/hip_runtime.h>
#include <stdint.h>

#define Nn 50000
#define Ee 800000
#define FIN 128
#define HIDD 256
#define CLSS 64

#define NBIN 98          // ceil(50000 / 512)
#define BSH 9
#define BINSZ 512
#define BCAP 16384
#define EPB 2048
#define NEB ((Ee + EPB - 1) / EPB)   // 391

typedef unsigned int uint_t;
typedef unsigned short us_t;
typedef __attribute__((ext_vector_type(8))) short short8;
typedef __attribute__((ext_vector_type(4))) float f32x4;

__device__ inline float bflo(uint_t v) { union { uint_t u; float f; } c; c.u = v << 16; return c.f; }
__device__ inline float bfhi(uint_t v) { union { uint_t u; float f; } c; c.u = v & 0xffff0000u; return c.f; }
__device__ inline us_t f2bf(float f) {
    union { float f; uint_t u; } c; c.f = f;
    uint_t u = c.u;
    u += 0x7fffu + ((u >> 16) & 1u);
    return (us_t)(u >> 16);
}

// ---------------- x convert, both sides in one launch ----------------
__global__ void k_cvtx(const float* __restrict__ xu, const float* __restrict__ xp,
                       us_t* __restrict__ ou, us_t* __restrict__ op, int n4) {
    const float* in = blockIdx.y ? xp : xu;
    us_t* out = blockIdx.y ? op : ou;
    int i = blockIdx.x * 256 + threadIdx.x;
    int stride = gridDim.x * 256;
    for (; i < n4; i += stride) {
        float4 v = reinterpret_cast<const float4*>(in)[i];
        ushort4 o;
        o.x = f2bf(v.x); o.y = f2bf(v.y); o.z = f2bf(v.z); o.w = f2bf(v.w);
        reinterpret_cast<ushort4*>(out)[i] = o;
    }
}

// ---------------- weight convert + bin_cnt zero (one launch) ----------------
__global__ void k_cvtw(const float* __restrict__ w1, const float* __restrict__ w2,
                       const float* __restrict__ w3, const float* __restrict__ w4,
                       const float* __restrict__ w5, const float* __restrict__ w6,
                       const float* __restrict__ w7, const float* __restrict__ w8,
                       us_t* __restrict__ o1, us_t* __restrict__ o2,
                       us_t* __restrict__ o3, us_t* __restrict__ o4,
                       us_t* __restrict__ o5, us_t* __restrict__ o6,
                       us_t* __restrict__ o7, us_t* __restrict__ o8,
                       int* __restrict__ bin_cnt) {
    if (blockIdx.x == 192) {
        int t = threadIdx.x;
        if (t < 2 * NBIN) bin_cnt[t] = 0;
        return;
    }
    int i = blockIdx.x * 256 + threadIdx.x;
    const float* wp; us_t* op; int loc;
    if (i < 32768) {
        int seg = i >> 13; loc = i & 8191;
        switch (seg) {
            case 0: wp = w1; op = o1; break;
            case 1: wp = w2; op = o2; break;
            case 2: wp = w3; op = o3; break;
            default: wp = w4; op = o4; break;
        }
    } else {
        int j = i - 32768;
        int seg = j >> 12; loc = j & 4095;
        switch (seg) {
            case 0: wp = w5; op = o5; break;
            case 1: wp = w6; op = o6; break;
            case 2: wp = w7; op = o7; break;
            default: wp = w8; op = o8; break;
        }
    }
    float4 v = reinterpret_cast<const float4*>(wp)[loc];
    ushort4 o;
    o.x = f2bf(v.x); o.y = f2bf(v.y); o.z = f2bf(v.z); o.w = f2bf(v.w);
    reinterpret_cast<ushort4*>(op)[loc] = o;
}

// ---------------- binned CSR build ----------------
__global__ __launch_bounds__(256) void k_bin(const int* __restrict__ ei,
                                             int* __restrict__ bin_cnt,
                                             uint_t* __restrict__ ent_p,
                                             uint_t* __restrict__ ent_u) {
    __shared__ int hist[2 * NBIN];
    __shared__ int base[2 * NBIN];
    int tid = threadIdx.x;
    int e0 = blockIdx.x * EPB;
    int n = Ee - e0; if (n > EPB) n = EPB;

    for (int i = tid; i < 2 * NBIN; i += 256) hist[i] = 0;
    __syncthreads();
    for (int i = tid; i < n; i += 256) {
        int u = ei[e0 + i], p = ei[Ee + e0 + i];
        atomicAdd(&hist[p >> BSH], 1);
        atomicAdd(&hist[NBIN + (u >> BSH)], 1);
    }
    __syncthreads();
    for (int i = tid; i < 2 * NBIN; i += 256) {
        int c = hist[i];
        base[i] = c ? atomicAdd(&bin_cnt[i], c) : 0;
    }
    __syncthreads();
    for (int i = tid; i < 2 * NBIN; i += 256) hist[i] = base[i];
    __syncthreads();
    for (int i = tid; i < n; i += 256) {
        int u = ei[e0 + i], p = ei[Ee + e0 + i];
        int bp = p >> BSH, bu = u >> BSH;
        int rp = atomicAdd(&hist[bp], 1);
        if (rp < BCAP)
            ent_p[(size_t)bp * BCAP + rp] = ((uint_t)(p & (BINSZ - 1)) << 16) | (uint_t)u;
        int ru = atomicAdd(&hist[NBIN + bu], 1);
        if (ru < BCAP)
            ent_u[(size_t)bu * BCAP + ru] = ((uint_t)(u & (BINSZ - 1)) << 16) | (uint_t)p;
    }
}

__global__ void k_binscan(const int* __restrict__ bin_cnt, int* __restrict__ bin_base) {
    __shared__ int buf[2][128];
    int t = threadIdx.x;
    int side = t >> 7, i = t & 127;
    int v = 0;
    if (i < NBIN) { v = bin_cnt[side * NBIN + i]; if (v > BCAP) v = BCAP; }
    buf[side][i] = v;
    __syncthreads();
    #pragma unroll
    for (int d = 1; d < 128; d <<= 1) {
        int x = (i >= d) ? buf[side][i - d] : 0;
        __syncthreads();
        buf[side][i] += x;
        __syncthreads();
    }
    if (i < NBIN) bin_base[side * NBIN + i] = buf[side][i] - v;
}

__global__ __launch_bounds__(512) void k_scatter(
    const uint_t* __restrict__ ent_p, const uint_t* __restrict__ ent_u,
    const int* __restrict__ bin_cnt, const int* __restrict__ bin_base,
    int* __restrict__ off, int* __restrict__ cnt,
    int* __restrict__ src_p, int* __restrict__ src_u) {
    __shared__ int ca[BINSZ];
    __shared__ int cb[BINSZ];
    int side = blockIdx.y, b = blockIdx.x, t = threadIdx.x;
    const uint_t* E = (side ? ent_u : ent_p) + (size_t)b * BCAP;
    int* src = side ? src_u : src_p;
    int nb = bin_cnt[side * NBIN + b]; if (nb > BCAP) nb = BCAP;
    int base = bin_base[side * NBIN + b];

    ca[t] = 0;
    __syncthreads();
    for (int i = t; i < nb; i += 512)
        atomicAdd(&ca[E[i] >> 16], 1);
    __syncthreads();
    int v = ca[t];
    int* A = ca; int* B = cb;
    #pragma unroll
    for (int d = 1; d < BINSZ; d <<= 1) {
        int x = A[t] + ((t >= d) ? A[t - d] : 0);
        B[t] = x;
        __syncthreads();
        int* tmp = A; A = B; B = tmp;
    }
    int excl = A[t] - v;
    B[t] = excl;
    __syncthreads();
    for (int i = t; i < nb; i += 512) {
        uint_t e = E[i];
        int sl = atomicAdd(&B[e >> 16], 1);
        src[base + sl] = (int)(e & 0xffffu);
    }
    int d = (b << BSH) + t;
    if (d < Nn) {
        off[side * Nn + d] = base + excl;
        cnt[side * Nn + d] = v;
    }
}

// ---------------- layer-1 mean aggregation, K-chunked for L2 residency ----------------
// phase = side*4 + chunk; chunk covers dims [32c, 32c+32) -> 3.2 MB table slice < 4 MB L2.
// 16 lanes per node (1 dword = 2 bf16 per lane), 8-deep gather ILP.
__global__ __launch_bounds__(256) void k_agg1(
    const us_t* __restrict__ xu, const us_t* __restrict__ xp,
    const int* __restrict__ off, const int* __restrict__ cnt,
    const int* __restrict__ src_p, const int* __restrict__ src_u,
    us_t* __restrict__ mu, us_t* __restrict__ mp) {
    int phase = blockIdx.z;
    int side = phase >> 2, chunk = phase & 3;
    const us_t* X = (side ? xp : xu) + 32 * chunk;
    const int* of = off + side * Nn;
    const int* cn = cnt + side * Nn;
    const int* sr = side ? src_u : src_p;
    us_t* out = (side ? mp : mu) + 32 * chunk;

    int node = blockIdx.x * 16 + (threadIdx.x >> 4);
    if (node >= Nn) return;
    int l = threadIdx.x & 15;
    int s = of[node], c = cn[node];
    float ax = 0.f, ay = 0.f;
    int j = 0;
    for (; j + 8 <= c; j += 8) {
        int ss[8];
        #pragma unroll
        for (int q = 0; q < 8; ++q) ss[q] = sr[s + j + q];
        uint_t vv[8];
        #pragma unroll
        for (int q = 0; q < 8; ++q)
            vv[q] = reinterpret_cast<const uint_t*>(X + (size_t)ss[q] * 128)[l];
        #pragma unroll
        for (int q = 0; q < 8; ++q) { ax += bflo(vv[q]); ay += bfhi(vv[q]); }
    }
    for (; j < c; ++j) {
        int s0 = sr[s + j];
        uint_t v0 = reinterpret_cast<const uint_t*>(X + (size_t)s0 * 128)[l];
        ax += bflo(v0); ay += bfhi(v0);
    }
    float inv = 1.0f / fmaxf((float)c, 1.0f);
    uint_t pack = (uint_t)f2bf(ax * inv) | ((uint_t)f2bf(ay * inv) << 16);
    reinterpret_cast<uint_t*>(out + (size_t)node * 128)[l] = pack;
}

// ---------------- layer-2 mean aggregation, K-chunked, accumulates into f32 out ----------------
// phase = side*2 + chunk; chunk covers dims [32c, 32c+32) of the 64-dim transformed rows.
__global__ __launch_bounds__(256) void k_agg2(
    const us_t* __restrict__ tu, const us_t* __restrict__ tp,
    const int* __restrict__ off, const int* __restrict__ cnt,
    const int* __restrict__ src_p, const int* __restrict__ src_u,
    float* __restrict__ ou, float* __restrict__ op) {
    int phase = blockIdx.z;
    int side = phase >> 1, chunk = phase & 1;
    const us_t* T = (side ? tp : tu) + 32 * chunk;
    const int* of = off + side * Nn;
    const int* cn = cnt + side * Nn;
    const int* sr = side ? src_u : src_p;
    float* out = (side ? op : ou) + 32 * chunk;

    int node = blockIdx.x * 16 + (threadIdx.x >> 4);
    if (node >= Nn) return;
    int l = threadIdx.x & 15;
    int s = of[node], c = cn[node];
    float ax = 0.f, ay = 0.f;
    int j = 0;
    for (; j + 8 <= c; j += 8) {
        int ss[8];
        #pragma unroll
        for (int q = 0; q < 8; ++q) ss[q] = sr[s + j + q];
        uint_t vv[8];
        #pragma unroll
        for (int q = 0; q < 8; ++q)
            vv[q] = reinterpret_cast<const uint_t*>(T + (size_t)ss[q] * 64)[l];
        #pragma unroll
        for (int q = 0; q < 8; ++q) { ax += bflo(vv[q]); ay += bfhi(vv[q]); }
    }
    for (; j < c; ++j) {
        int s0 = sr[s + j];
        uint_t v0 = reinterpret_cast<const uint_t*>(T + (size_t)s0 * 64)[l];
        ax += bflo(v0); ay += bfhi(v0);
    }
    float inv = 1.0f / fmaxf((float)c, 1.0f);
    float2* o = reinterpret_cast<float2*>(out + (size_t)node * 64) + l;
    float2 p = *o;
    p.x += ax * inv; p.y += ay * inv;
    *o = p;
}

// ---------------- MFMA GEMM core macros ----------------
#define MM_STAGE(Ap, Wp, K, BN, KSLOT)                                              \
    do {                                                                            \
        _Pragma("unroll")                                                           \
        for (int ii = 0; ii < (64 * KSLOT) / 256; ++ii) {                           \
            int s_ = ii * 256 + tid;                                                \
            int row = s_ / KSLOT, ks = s_ % KSLOT;                                  \
            int ksl = ks ^ (row & 7);                                               \
            int grow = node_base + row; if (grow >= Nn) grow = Nn - 1;              \
            const void* g = (Ap) + (size_t)grow * K + ksl * 8;                      \
            __builtin_amdgcn_global_load_lds(                                       \
                (const __attribute__((address_space(1))) unsigned int*)g,           \
                (__attribute__((address_space(3))) unsigned int*)&sA[(s_ - lane) * 8], \
                16, 0, 0);                                                          \
        }                                                                           \
        _Pragma("unroll")                                                           \
        for (int ii = 0; ii < (BN * KSLOT) / 256; ++ii) {                           \
            int s_ = ii * 256 + tid;                                                \
            int row = s_ / KSLOT, ks = s_ % KSLOT;                                  \
            int ksl = ks ^ (row & 7);                                               \
            const void* g = (Wp) + (size_t)(out_base + row) * K + ksl * 8;          \
            __builtin_amdgcn_global_load_lds(                                       \
                (const __attribute__((address_space(1))) unsigned int*)g,           \
                (__attribute__((address_space(3))) unsigned int*)&sW[(s_ - lane) * 8], \
                16, 0, 0);                                                          \
        }                                                                           \
        asm volatile("s_waitcnt vmcnt(0)" ::: "memory");                            \
        __syncthreads();                                                            \
    } while (0)

#define MM_COMPUTE(K, BN, FN)                                                       \
    do {                                                                            \
        _Pragma("unroll")                                                           \
        for (int ks = 0; ks < K / 32; ++ks) {                                       \
            short8 af[2], bfr[FN];                                                  \
            _Pragma("unroll")                                                       \
            for (int m = 0; m < 2; ++m) {                                           \
                int row = wr * 32 + m * 16 + (lane & 15);                           \
                int ksl = (ks * 4 + (lane >> 4)) ^ (row & 7);                       \
                af[m] = *reinterpret_cast<const short8*>(&sA[row * K + ksl * 8]);   \
            }                                                                       \
            _Pragma("unroll")                                                       \
            for (int n = 0; n < FN; ++n) {                                          \
                int row = wc * (BN / 2) + n * 16 + (lane & 15);                     \
                int ksl = (ks * 4 + (lane >> 4)) ^ (row & 7);                       \
                bfr[n] = *reinterpret_cast<const short8*>(&sW[row * K + ksl * 8]);  \
            }                                                                       \
            _Pragma("unroll")                                                       \
            for (int m = 0; m < 2; ++m)                                             \
                _Pragma("unroll")                                                   \
                for (int n = 0; n < FN; ++n)                                        \
                    acc[m][n] = __builtin_amdgcn_mfma_f32_16x16x32_bf16(            \
                        af[m], bfr[n], acc[m][n], 0, 0, 0);                         \
        }                                                                           \
    } while (0)

// ---------------- layer-1 dual GEMM, both sides: blockIdx.z = job ----------------
__global__ __launch_bounds__(256) void k_mm1(
    const us_t* __restrict__ mu, const us_t* __restrict__ mp,
    const us_t* __restrict__ xbu, const us_t* __restrict__ xbp,
    const us_t* __restrict__ wu1l, const us_t* __restrict__ wu1r,
    const us_t* __restrict__ wp1l, const us_t* __restrict__ wp1r,
    const float* __restrict__ bu1, const float* __restrict__ bp1,
    us_t* __restrict__ hu, us_t* __restrict__ hp) {
    constexpr int K = FIN, BN = 128, KSLOT = K / 8, FN = BN / 32;
    __shared__ us_t sA[64 * K];
    __shared__ us_t sW[BN * K];
    int tid = threadIdx.x, lane = tid & 63;
    int w = tid >> 6, wr = w >> 1, wc = w & 1;
    int node_base = blockIdx.x * 64, out_base = blockIdx.y * BN;
    int job = blockIdx.z;

    const us_t* A0 = job ? mp : mu;
    const us_t* A1 = job ? xbu : xbp;
    const us_t* W0 = job ? wp1l : wu1l;
    const us_t* W1 = job ? wp1r : wu1r;
    const float* bias = job ? bp1 : bu1;
    us_t* C = job ? hp : hu;

    f32x4 acc[2][FN];
    #pragma unroll
    for (int m = 0; m < 2; ++m)
        #pragma unroll
        for (int n = 0; n < FN; ++n)
            #pragma unroll
            for (int i = 0; i < 4; ++i) acc[m][n][i] = 0.f;

    MM_STAGE(A0, W0, K, BN, KSLOT);
    MM_COMPUTE(K, BN, FN);
    __syncthreads();
    MM_STAGE(A1, W1, K, BN, KSLOT);
    MM_COMPUTE(K, BN, FN);

    #pragma unroll
    for (int n = 0; n < FN; ++n) {
        int col = out_base + wc * (BN / 2) + n * 16 + (lane & 15);
        float bv = bias[col];
        #pragma unroll
        for (int m = 0; m < 2; ++m) {
            int row0 = node_base + wr * 32 + m * 16 + ((lane >> 4) << 2);
            #pragma unroll
            for (int j = 0; j < 4; ++j) {
                int row = row0 + j;
                if (row >= Nn) continue;
                float v = fmaxf(acc[m][n][j] + bv, 0.f);
                C[(size_t)row * HIDD + col] = f2bf(v);
            }
        }
    }
}

// ---------------- layer-2 GEMMs, 4 jobs: blockIdx.z ----------------
__global__ __launch_bounds__(256) void k_mm2(
    const us_t* __restrict__ hu, const us_t* __restrict__ hp,
    const us_t* __restrict__ wu2l, const us_t* __restrict__ wu2r,
    const us_t* __restrict__ wp2l, const us_t* __restrict__ wp2r,
    const float* __restrict__ bu2, const float* __restrict__ bp2,
    us_t* __restrict__ tu, us_t* __restrict__ tp,
    float* __restrict__ ou, float* __restrict__ op) {
    constexpr int K = HIDD, BN = 64, KSLOT = K / 8, FN = BN / 32;
    __shared__ us_t sA[64 * K];
    __shared__ us_t sW[BN * K];
    int tid = threadIdx.x, lane = tid & 63;
    int w = tid >> 6, wr = w >> 1, wc = w & 1;
    int node_base = blockIdx.x * 64, out_base = 0;
    int job = blockIdx.z;

    const us_t* A; const us_t* W;
    switch (job) {
        case 0: A = hu; W = wu2l; break;
        case 1: A = hp; W = wu2r; break;
        case 2: A = hp; W = wp2l; break;
        default: A = hu; W = wp2r; break;
    }

    f32x4 acc[2][FN];
    #pragma unroll
    for (int m = 0; m < 2; ++m)
        #pragma unroll
        for (int n = 0; n < FN; ++n)
            #pragma unroll
            for (int i = 0; i < 4; ++i) acc[m][n][i] = 0.f;

    MM_STAGE(A, W, K, BN, KSLOT);
    MM_COMPUTE(K, BN, FN);

    #pragma unroll
    for (int n = 0; n < FN; ++n) {
        int col = wc * (BN / 2) + n * 16 + (lane & 15);
        float bv = (job == 1) ? bu2[col] : (job == 3 ? bp2[col] : 0.f);
        #pragma unroll
        for (int m = 0; m < 2; ++m) {
            int row0 = node_base + wr * 32 + m * 16 + ((lane >> 4) << 2);
            #pragma unroll
            for (int j = 0; j < 4; ++j) {
                int row = row0 + j;
                if (row >= Nn) continue;
                float v = acc[m][n][j] + bv;
                if (job == 0)       tu[(size_t)row * CLSS + col] = f2bf(v);
                else if (job == 2)  tp[(size_t)row * CLSS + col] = f2bf(v);
                else if (job == 1)  ou[(size_t)row * CLSS + col] = v;
                else                op[(size_t)row * CLSS + col] = v;
            }
        }
    }
}

// ---------------- launch ----------------
extern "C" void kernel_launch(void* const* d_in, const int* in_sizes, int n_in,
                              void* d_out, int out_size, void* d_ws, size_t ws_size,
                              hipStream_t stream) {
    const float* x_user    = (const float*)d_in[0];
    const float* x_product = (const float*)d_in[1];
    const int*   ei        = (const int*)d_in[2];
    const float* w_u1_l = (const float*)d_in[3];
    const float* b_u1   = (const float*)d_in[4];
    const float* w_u1_r = (const float*)d_in[5];
    const float* w_p1_l = (const float*)d_in[6];
    const float* b_p1   = (const float*)d_in[7];
    const float* w_p1_r = (const float*)d_in[8];
    const float* w_u2_l = (const float*)d_in[9];
    const float* b_u2   = (const float*)d_in[10];
    const float* w_u2_r = (const float*)d_in[11];
    const float* w_p2_l = (const float*)d_in[12];
    const float* b_p2   = (const float*)d_in[13];
    const float* w_p2_r = (const float*)d_in[14];

    float* out_u = (float*)d_out;
    float* out_p = out_u + (size_t)Nn * CLSS;

    char* w = (char*)d_ws;
    int* bin_cnt  = (int*)w; w += (size_t)2 * NBIN * 4;
    int* bin_base = (int*)w; w += (size_t)2 * NBIN * 4;
    int* off  = (int*)w;  w += (size_t)2 * Nn * 4;
    int* cnt  = (int*)w;  w += (size_t)2 * Nn * 4;
    int* src_p = (int*)w; w += (size_t)Ee * 4;
    int* src_u = (int*)w; w += (size_t)Ee * 4;
    uint_t* ent_p = (uint_t*)w; w += (size_t)NBIN * BCAP * 4;
    uint_t* ent_u = (uint_t*)w; w += (size_t)NBIN * BCAP * 4;
    uintptr_t a = (uintptr_t)w; a = (a + 255) & ~(uintptr_t)255; w = (char*)a;
    us_t* xbu  = (us_t*)w; w += (size_t)Nn * FIN * 2;
    us_t* xbp  = (us_t*)w; w += (size_t)Nn * FIN * 2;
    us_t* h_u  = (us_t*)w; w += (size_t)Nn * HIDD * 2;
    us_t* h_p  = (us_t*)w; w += (size_t)Nn * HIDD * 2;
    us_t* mean_u = (us_t*)w; w += (size_t)Nn * FIN * 2;
    us_t* mean_p = (us_t*)w; w += (size_t)Nn * FIN * 2;
    us_t* tbuf_u = (us_t*)w; w += (size_t)Nn * CLSS * 2;
    us_t* tbuf_p = (us_t*)w; w += (size_t)Nn * CLSS * 2;
    us_t* wb_u1l = (us_t*)w; w += (size_t)HIDD * FIN * 2;
    us_t* wb_u1r = (us_t*)w; w += (size_t)HIDD * FIN * 2;
    us_t* wb_p1l = (us_t*)w; w += (size_t)HIDD * FIN * 2;
    us_t* wb_p1r = (us_t*)w; w += (size_t)HIDD * FIN * 2;
    us_t* wb_u2l = (us_t*)w; w += (size_t)CLSS * HIDD * 2;
    us_t* wb_u2r = (us_t*)w; w += (size_t)CLSS * HIDD * 2;
    us_t* wb_p2l = (us_t*)w; w += (size_t)CLSS * HIDD * 2;
    us_t* wb_p2r = (us_t*)w; w += (size_t)CLSS * HIDD * 2;

    // conversions + bin_cnt zero
    {
        int n4 = (Nn * FIN) / 4;
        int blocks = (n4 + 255) / 256; if (blocks > 1024) blocks = 1024;
        dim3 g(blocks, 2);
        k_cvtx<<<g, 256, 0, stream>>>(x_user, x_product, xbu, xbp, n4);
    }
    k_cvtw<<<193, 256, 0, stream>>>(w_u1_l, w_u1_r, w_p1_l, w_p1_r,
                                    w_u2_l, w_u2_r, w_p2_l, w_p2_r,
                                    wb_u1l, wb_u1r, wb_p1l, wb_p1r,
                                    wb_u2l, wb_u2r, wb_p2l, wb_p2r, bin_cnt);

    // binned CSR build
    k_bin<<<NEB, 256, 0, stream>>>(ei, bin_cnt, ent_p, ent_u);
    k_binscan<<<1, 256, 0, stream>>>(bin_cnt, bin_base);
    dim3 gsc(NBIN, 2);
    k_scatter<<<gsc, 512, 0, stream>>>(ent_p, ent_u, bin_cnt, bin_base,
                                       off, cnt, src_p, src_u);

    // ---- layer 1 ----
    dim3 ga1((Nn + 15) / 16, 1, 8);           // z = side*4 + chunk
    k_agg1<<<ga1, 256, 0, stream>>>(xbu, xbp, off, cnt, src_p, src_u, mean_u, mean_p);
    dim3 g1((Nn + 63) / 64, HIDD / 128, 2);
    k_mm1<<<g1, 256, 0, stream>>>(mean_u, mean_p, xbu, xbp,
                                  wb_u1l, wb_u1r, wb_p1l, wb_p1r,
                                  b_u1, b_p1, h_u, h_p);

    // ---- layer 2 ----
    dim3 g2((Nn + 63) / 64, 1, 4);
    k_mm2<<<g2, 256, 0, stream>>>(h_u, h_p, wb_u2l, wb_u2r, wb_p2l, wb_p2r,
                                  b_u2, b_p2, tbuf_u, tbuf_p, out_u, out_p);
    dim3 ga2((Nn + 15) / 16, 1, 4);           // z = side*2 + chunk
    k_agg2<<<ga2, 256, 0, stream>>>(tbuf_u, tbuf_p, off, cnt, src_p, src_u, out_u, out_p);
}

// Round 6
// 218.841 us; speedup vs baseline: 1.3026x; 1.3026x over previous
//
#include <hip/hip_runtime.h>
#include <stdint.h>

#define Nn 50000
#define Ee 800000
#define FIN 128
#define HIDD 256
#define CLSS 64

#define NBIN 98          // ceil(50000 / 512)
#define BSH 9
#define BINSZ 512
#define BCAP 16384
#define EPB 2048
#define NEB ((Ee + EPB - 1) / EPB)   // 391

typedef unsigned int uint_t;
typedef unsigned short us_t;
typedef __attribute__((ext_vector_type(8))) short short8;
typedef __attribute__((ext_vector_type(4))) float f32x4;
typedef __attribute__((ext_vector_type(2))) float f32x2;

__device__ inline float bflo(uint_t v) { union { uint_t u; float f; } c; c.u = v << 16; return c.f; }
__device__ inline float bfhi(uint_t v) { union { uint_t u; float f; } c; c.u = v & 0xffff0000u; return c.f; }
__device__ inline us_t f2bf(float f) {
    union { float f; uint_t u; } c; c.f = f;
    uint_t u = c.u;
    u += 0x7fffu + ((u >> 16) & 1u);
    return (us_t)(u >> 16);
}

// ---------------- x convert: bf16 (for GEMM) + fp8 (for gather), one pass ----------------
__global__ void k_cvtx(const float* __restrict__ xu, const float* __restrict__ xp,
                       us_t* __restrict__ ou, us_t* __restrict__ op,
                       uint_t* __restrict__ f8u, uint_t* __restrict__ f8p, int n4) {
    const float* in = blockIdx.y ? xp : xu;
    us_t* out = blockIdx.y ? op : ou;
    uint_t* o8 = blockIdx.y ? f8p : f8u;
    int i = blockIdx.x * 256 + threadIdx.x;
    int stride = gridDim.x * 256;
    for (; i < n4; i += stride) {
        float4 v = reinterpret_cast<const float4*>(in)[i];
        ushort4 o;
        o.x = f2bf(v.x); o.y = f2bf(v.y); o.z = f2bf(v.z); o.w = f2bf(v.w);
        reinterpret_cast<ushort4*>(out)[i] = o;
        int pk = __builtin_amdgcn_cvt_pk_fp8_f32(v.x, v.y, 0, false);
        pk = __builtin_amdgcn_cvt_pk_fp8_f32(v.z, v.w, pk, true);
        o8[i] = (uint_t)pk;
    }
}

// ---------------- weight convert + bin_cnt zero (one launch) ----------------
__global__ void k_cvtw(const float* __restrict__ w1, const float* __restrict__ w2,
                       const float* __restrict__ w3, const float* __restrict__ w4,
                       const float* __restrict__ w5, const float* __restrict__ w6,
                       const float* __restrict__ w7, const float* __restrict__ w8,
                       us_t* __restrict__ o1, us_t* __restrict__ o2,
                       us_t* __restrict__ o3, us_t* __restrict__ o4,
                       us_t* __restrict__ o5, us_t* __restrict__ o6,
                       us_t* __restrict__ o7, us_t* __restrict__ o8,
                       int* __restrict__ bin_cnt) {
    if (blockIdx.x == 192) {
        int t = threadIdx.x;
        if (t < 2 * NBIN) bin_cnt[t] = 0;
        return;
    }
    int i = blockIdx.x * 256 + threadIdx.x;
    const float* wp; us_t* op; int loc;
    if (i < 32768) {
        int seg = i >> 13; loc = i & 8191;
        switch (seg) {
            case 0: wp = w1; op = o1; break;
            case 1: wp = w2; op = o2; break;
            case 2: wp = w3; op = o3; break;
            default: wp = w4; op = o4; break;
        }
    } else {
        int j = i - 32768;
        int seg = j >> 12; loc = j & 4095;
        switch (seg) {
            case 0: wp = w5; op = o5; break;
            case 1: wp = w6; op = o6; break;
            case 2: wp = w7; op = o7; break;
            default: wp = w8; op = o8; break;
        }
    }
    float4 v = reinterpret_cast<const float4*>(wp)[loc];
    ushort4 o;
    o.x = f2bf(v.x); o.y = f2bf(v.y); o.z = f2bf(v.z); o.w = f2bf(v.w);
    reinterpret_cast<ushort4*>(op)[loc] = o;
}

// ---------------- binned CSR build ----------------
__global__ __launch_bounds__(256) void k_bin(const int* __restrict__ ei,
                                             int* __restrict__ bin_cnt,
                                             uint_t* __restrict__ ent_p,
                                             uint_t* __restrict__ ent_u) {
    __shared__ int hist[2 * NBIN];
    __shared__ int base[2 * NBIN];
    int tid = threadIdx.x;
    int e0 = blockIdx.x * EPB;
    int n = Ee - e0; if (n > EPB) n = EPB;

    for (int i = tid; i < 2 * NBIN; i += 256) hist[i] = 0;
    __syncthreads();
    for (int i = tid; i < n; i += 256) {
        int u = ei[e0 + i], p = ei[Ee + e0 + i];
        atomicAdd(&hist[p >> BSH], 1);
        atomicAdd(&hist[NBIN + (u >> BSH)], 1);
    }
    __syncthreads();
    for (int i = tid; i < 2 * NBIN; i += 256) {
        int c = hist[i];
        base[i] = c ? atomicAdd(&bin_cnt[i], c) : 0;
    }
    __syncthreads();
    for (int i = tid; i < 2 * NBIN; i += 256) hist[i] = base[i];
    __syncthreads();
    for (int i = tid; i < n; i += 256) {
        int u = ei[e0 + i], p = ei[Ee + e0 + i];
        int bp = p >> BSH, bu = u >> BSH;
        int rp = atomicAdd(&hist[bp], 1);
        if (rp < BCAP)
            ent_p[(size_t)bp * BCAP + rp] = ((uint_t)(p & (BINSZ - 1)) << 16) | (uint_t)u;
        int ru = atomicAdd(&hist[NBIN + bu], 1);
        if (ru < BCAP)
            ent_u[(size_t)bu * BCAP + ru] = ((uint_t)(u & (BINSZ - 1)) << 16) | (uint_t)p;
    }
}

__global__ void k_binscan(const int* __restrict__ bin_cnt, int* __restrict__ bin_base) {
    __shared__ int buf[2][128];
    int t = threadIdx.x;
    int side = t >> 7, i = t & 127;
    int v = 0;
    if (i < NBIN) { v = bin_cnt[side * NBIN + i]; if (v > BCAP) v = BCAP; }
    buf[side][i] = v;
    __syncthreads();
    #pragma unroll
    for (int d = 1; d < 128; d <<= 1) {
        int x = (i >= d) ? buf[side][i - d] : 0;
        __syncthreads();
        buf[side][i] += x;
        __syncthreads();
    }
    if (i < NBIN) bin_base[side * NBIN + i] = buf[side][i] - v;
}

__global__ __launch_bounds__(512) void k_scatter(
    const uint_t* __restrict__ ent_p, const uint_t* __restrict__ ent_u,
    const int* __restrict__ bin_cnt, const int* __restrict__ bin_base,
    int* __restrict__ off, int* __restrict__ cnt,
    int* __restrict__ src_p, int* __restrict__ src_u) {
    __shared__ int ca[BINSZ];
    __shared__ int cb[BINSZ];
    int side = blockIdx.y, b = blockIdx.x, t = threadIdx.x;
    const uint_t* E = (side ? ent_u : ent_p) + (size_t)b * BCAP;
    int* src = side ? src_u : src_p;
    int nb = bin_cnt[side * NBIN + b]; if (nb > BCAP) nb = BCAP;
    int base = bin_base[side * NBIN + b];

    ca[t] = 0;
    __syncthreads();
    for (int i = t; i < nb; i += 512)
        atomicAdd(&ca[E[i] >> 16], 1);
    __syncthreads();
    int v = ca[t];
    int* A = ca; int* B = cb;
    #pragma unroll
    for (int d = 1; d < BINSZ; d <<= 1) {
        int x = A[t] + ((t >= d) ? A[t - d] : 0);
        B[t] = x;
        __syncthreads();
        int* tmp = A; A = B; B = tmp;
    }
    int excl = A[t] - v;
    B[t] = excl;
    __syncthreads();
    for (int i = t; i < nb; i += 512) {
        uint_t e = E[i];
        int sl = atomicAdd(&B[e >> 16], 1);
        src[base + sl] = (int)(e & 0xffffu);
    }
    int d = (b << BSH) + t;
    if (d < Nn) {
        off[side * Nn + d] = base + excl;
        cnt[side * Nn + d] = v;
    }
}

// ---------------- layer-1 mean aggregation from fp8 table, bf16 mean out ----------------
// 16 lanes/node, uint2 = 8 fp8 per lane (full 128-dim row = 128B), ILP-8.
__global__ __launch_bounds__(256) void k_agg1(
    const uint2* __restrict__ xu8, const uint2* __restrict__ xp8,
    const int* __restrict__ off, const int* __restrict__ cnt,
    const int* __restrict__ src_p, const int* __restrict__ src_u,
    us_t* __restrict__ mu, us_t* __restrict__ mp) {
    int side = blockIdx.y;
    const uint2* X = side ? xp8 : xu8;
    const int* of = off + side * Nn;
    const int* cn = cnt + side * Nn;
    const int* sr = side ? src_u : src_p;
    us_t* out = side ? mp : mu;

    int node = blockIdx.x * 16 + (threadIdx.x >> 4);
    if (node >= Nn) return;
    int l = threadIdx.x & 15;
    int s = of[node], c = cn[node];
    float a0=0.f,a1=0.f,a2=0.f,a3=0.f,a4=0.f,a5=0.f,a6=0.f,a7=0.f;
    int j = 0;
    for (; j + 8 <= c; j += 8) {
        int ss[8];
        #pragma unroll
        for (int q = 0; q < 8; ++q) ss[q] = sr[s + j + q];
        uint2 vv[8];
        #pragma unroll
        for (int q = 0; q < 8; ++q)
            vv[q] = X[(size_t)ss[q] * 16 + l];
        #pragma unroll
        for (int q = 0; q < 8; ++q) {
            f32x2 p0 = __builtin_amdgcn_cvt_pk_f32_fp8((int)vv[q].x, false);
            f32x2 p1 = __builtin_amdgcn_cvt_pk_f32_fp8((int)vv[q].x, true);
            f32x2 p2 = __builtin_amdgcn_cvt_pk_f32_fp8((int)vv[q].y, false);
            f32x2 p3 = __builtin_amdgcn_cvt_pk_f32_fp8((int)vv[q].y, true);
            a0 += p0[0]; a1 += p0[1]; a2 += p1[0]; a3 += p1[1];
            a4 += p2[0]; a5 += p2[1]; a6 += p3[0]; a7 += p3[1];
        }
    }
    for (; j < c; ++j) {
        uint2 v0 = X[(size_t)sr[s + j] * 16 + l];
        f32x2 p0 = __builtin_amdgcn_cvt_pk_f32_fp8((int)v0.x, false);
        f32x2 p1 = __builtin_amdgcn_cvt_pk_f32_fp8((int)v0.x, true);
        f32x2 p2 = __builtin_amdgcn_cvt_pk_f32_fp8((int)v0.y, false);
        f32x2 p3 = __builtin_amdgcn_cvt_pk_f32_fp8((int)v0.y, true);
        a0 += p0[0]; a1 += p0[1]; a2 += p1[0]; a3 += p1[1];
        a4 += p2[0]; a5 += p2[1]; a6 += p3[0]; a7 += p3[1];
    }
    float inv = 1.0f / fmaxf((float)c, 1.0f);
    uint4 o;
    o.x = (uint_t)f2bf(a0 * inv) | ((uint_t)f2bf(a1 * inv) << 16);
    o.y = (uint_t)f2bf(a2 * inv) | ((uint_t)f2bf(a3 * inv) << 16);
    o.z = (uint_t)f2bf(a4 * inv) | ((uint_t)f2bf(a5 * inv) << 16);
    o.w = (uint_t)f2bf(a6 * inv) | ((uint_t)f2bf(a7 * inv) << 16);
    reinterpret_cast<uint4*>(out + (size_t)node * 128)[l] = o;
}

// ---------------- layer-2 mean aggregation (bf16 tbuf), adds into f32 out ----------------
// 16 lanes/node, uint2 = 4 bf16 per lane, ILP-4.
__global__ void k_agg2(const us_t* __restrict__ tu, const us_t* __restrict__ tp,
                       const int* __restrict__ off, const int* __restrict__ cnt,
                       const int* __restrict__ src_p, const int* __restrict__ src_u,
                       float* __restrict__ ou, float* __restrict__ op) {
    int side = blockIdx.y;
    const us_t* T = side ? tp : tu;
    const int* of = off + side * Nn;
    const int* cn = cnt + side * Nn;
    const int* sr = side ? src_u : src_p;
    float* out = side ? op : ou;

    int node = blockIdx.x * 16 + (threadIdx.x >> 4);
    if (node >= Nn) return;
    int sl = threadIdx.x & 15;
    int s = of[node], c = cn[node];
    float a0 = 0.f, a1 = 0.f, a2 = 0.f, a3 = 0.f;
    int j = 0;
    for (; j + 4 <= c; j += 4) {
        int ss[4];
        #pragma unroll
        for (int q = 0; q < 4; ++q) ss[q] = sr[s + j + q];
        uint2 vv[4];
        #pragma unroll
        for (int q = 0; q < 4; ++q)
            vv[q] = reinterpret_cast<const uint2*>(T + (size_t)ss[q] * 64)[sl];
        #pragma unroll
        for (int q = 0; q < 4; ++q) {
            a0 += bflo(vv[q].x); a1 += bfhi(vv[q].x);
            a2 += bflo(vv[q].y); a3 += bfhi(vv[q].y);
        }
    }
    for (; j < c; ++j) {
        int s0 = sr[s + j];
        uint2 v0 = reinterpret_cast<const uint2*>(T + (size_t)s0 * 64)[sl];
        a0 += bflo(v0.x); a1 += bfhi(v0.x); a2 += bflo(v0.y); a3 += bfhi(v0.y);
    }
    float inv = 1.0f / fmaxf((float)c, 1.0f);
    float4* o = reinterpret_cast<float4*>(out + (size_t)node * 64) + sl;
    float4 p = *o;
    p.x += a0 * inv; p.y += a1 * inv; p.z += a2 * inv; p.w += a3 * inv;
    *o = p;
}

// ---------------- MFMA GEMM core macros ----------------
#define MM_STAGE(Ap, Wp, K, BN, KSLOT)                                              \
    do {                                                                            \
        _Pragma("unroll")                                                           \
        for (int ii = 0; ii < (64 * KSLOT) / 256; ++ii) {                           \
            int s_ = ii * 256 + tid;                                                \
            int row = s_ / KSLOT, ks = s_ % KSLOT;                                  \
            int ksl = ks ^ (row & 7);                                               \
            int grow = node_base + row; if (grow >= Nn) grow = Nn - 1;              \
            const void* g = (Ap) + (size_t)grow * K + ksl * 8;                      \
            __builtin_amdgcn_global_load_lds(                                       \
                (const __attribute__((address_space(1))) unsigned int*)g,           \
                (__attribute__((address_space(3))) unsigned int*)&sA[(s_ - lane) * 8], \
                16, 0, 0);                                                          \
        }                                                                           \
        _Pragma("unroll")                                                           \
        for (int ii = 0; ii < (BN * KSLOT) / 256; ++ii) {                           \
            int s_ = ii * 256 + tid;                                                \
            int row = s_ / KSLOT, ks = s_ % KSLOT;                                  \
            int ksl = ks ^ (row & 7);                                               \
            const void* g = (Wp) + (size_t)(out_base + row) * K + ksl * 8;          \
            __builtin_amdgcn_global_load_lds(                                       \
                (const __attribute__((address_space(1))) unsigned int*)g,           \
                (__attribute__((address_space(3))) unsigned int*)&sW[(s_ - lane) * 8], \
                16, 0, 0);                                                          \
        }                                                                           \
        asm volatile("s_waitcnt vmcnt(0)" ::: "memory");                            \
        __syncthreads();                                                            \
    } while (0)

#define MM_COMPUTE(K, BN, FN)                                                       \
    do {                                                                            \
        _Pragma("unroll")                                                           \
        for (int ks = 0; ks < K / 32; ++ks) {                                       \
            short8 af[2], bfr[FN];                                                  \
            _Pragma("unroll")                                                       \
            for (int m = 0; m < 2; ++m) {                                           \
                int row = wr * 32 + m * 16 + (lane & 15);                           \
                int ksl = (ks * 4 + (lane >> 4)) ^ (row & 7);                       \
                af[m] = *reinterpret_cast<const short8*>(&sA[row * K + ksl * 8]);   \
            }                                                                       \
            _Pragma("unroll")                                                       \
            for (int n = 0; n < FN; ++n) {                                          \
                int row = wc * (BN / 2) + n * 16 + (lane & 15);                     \
                int ksl = (ks * 4 + (lane >> 4)) ^ (row & 7);                       \
                bfr[n] = *reinterpret_cast<const short8*>(&sW[row * K + ksl * 8]);  \
            }                                                                       \
            _Pragma("unroll")                                                       \
            for (int m = 0; m < 2; ++m)                                             \
                _Pragma("unroll")                                                   \
                for (int n = 0; n < FN; ++n)                                        \
                    acc[m][n] = __builtin_amdgcn_mfma_f32_16x16x32_bf16(            \
                        af[m], bfr[n], acc[m][n], 0, 0, 0);                         \
        }                                                                           \
    } while (0)

// ---------------- layer-1 dual GEMM, both sides: blockIdx.z = job ----------------
__global__ __launch_bounds__(256) void k_mm1(
    const us_t* __restrict__ mu, const us_t* __restrict__ mp,
    const us_t* __restrict__ xbu, const us_t* __restrict__ xbp,
    const us_t* __restrict__ wu1l, const us_t* __restrict__ wu1r,
    const us_t* __restrict__ wp1l, const us_t* __restrict__ wp1r,
    const float* __restrict__ bu1, const float* __restrict__ bp1,
    us_t* __restrict__ hu, us_t* __restrict__ hp) {
    constexpr int K = FIN, BN = 128, KSLOT = K / 8, FN = BN / 32;
    __shared__ us_t sA[64 * K];
    __shared__ us_t sW[BN * K];
    int tid = threadIdx.x, lane = tid & 63;
    int w = tid >> 6, wr = w >> 1, wc = w & 1;
    int node_base = blockIdx.x * 64, out_base = blockIdx.y * BN;
    int job = blockIdx.z;

    const us_t* A0 = job ? mp : mu;
    const us_t* A1 = job ? xbu : xbp;
    const us_t* W0 = job ? wp1l : wu1l;
    const us_t* W1 = job ? wp1r : wu1r;
    const float* bias = job ? bp1 : bu1;
    us_t* C = job ? hp : hu;

    f32x4 acc[2][FN];
    #pragma unroll
    for (int m = 0; m < 2; ++m)
        #pragma unroll
        for (int n = 0; n < FN; ++n)
            #pragma unroll
            for (int i = 0; i < 4; ++i) acc[m][n][i] = 0.f;

    MM_STAGE(A0, W0, K, BN, KSLOT);
    MM_COMPUTE(K, BN, FN);
    __syncthreads();
    MM_STAGE(A1, W1, K, BN, KSLOT);
    MM_COMPUTE(K, BN, FN);

    #pragma unroll
    for (int n = 0; n < FN; ++n) {
        int col = out_base + wc * (BN / 2) + n * 16 + (lane & 15);
        float bv = bias[col];
        #pragma unroll
        for (int m = 0; m < 2; ++m) {
            int row0 = node_base + wr * 32 + m * 16 + ((lane >> 4) << 2);
            #pragma unroll
            for (int j = 0; j < 4; ++j) {
                int row = row0 + j;
                if (row >= Nn) continue;
                float v = fmaxf(acc[m][n][j] + bv, 0.f);
                C[(size_t)row * HIDD + col] = f2bf(v);
            }
        }
    }
}

// ---------------- layer-2 GEMMs, 4 jobs: blockIdx.z ----------------
__global__ __launch_bounds__(256) void k_mm2(
    const us_t* __restrict__ hu, const us_t* __restrict__ hp,
    const us_t* __restrict__ wu2l, const us_t* __restrict__ wu2r,
    const us_t* __restrict__ wp2l, const us_t* __restrict__ wp2r,
    const float* __restrict__ bu2, const float* __restrict__ bp2,
    us_t* __restrict__ tu, us_t* __restrict__ tp,
    float* __restrict__ ou, float* __restrict__ op) {
    constexpr int K = HIDD, BN = 64, KSLOT = K / 8, FN = BN / 32;
    __shared__ us_t sA[64 * K];
    __shared__ us_t sW[BN * K];
    int tid = threadIdx.x, lane = tid & 63;
    int w = tid >> 6, wr = w >> 1, wc = w & 1;
    int node_base = blockIdx.x * 64, out_base = 0;
    int job = blockIdx.z;

    const us_t* A; const us_t* W;
    switch (job) {
        case 0: A = hu; W = wu2l; break;
        case 1: A = hp; W = wu2r; break;
        case 2: A = hp; W = wp2l; break;
        default: A = hu; W = wp2r; break;
    }

    f32x4 acc[2][FN];
    #pragma unroll
    for (int m = 0; m < 2; ++m)
        #pragma unroll
        for (int n = 0; n < FN; ++n)
            #pragma unroll
            for (int i = 0; i < 4; ++i) acc[m][n][i] = 0.f;

    MM_STAGE(A, W, K, BN, KSLOT);
    MM_COMPUTE(K, BN, FN);

    #pragma unroll
    for (int n = 0; n < FN; ++n) {
        int col = wc * (BN / 2) + n * 16 + (lane & 15);
        float bv = (job == 1) ? bu2[col] : (job == 3 ? bp2[col] : 0.f);
        #pragma unroll
        for (int m = 0; m < 2; ++m) {
            int row0 = node_base + wr * 32 + m * 16 + ((lane >> 4) << 2);
            #pragma unroll
            for (int j = 0; j < 4; ++j) {
                int row = row0 + j;
                if (row >= Nn) continue;
                float v = acc[m][n][j] + bv;
                if (job == 0)       tu[(size_t)row * CLSS + col] = f2bf(v);
                else if (job == 2)  tp[(size_t)row * CLSS + col] = f2bf(v);
                else if (job == 1)  ou[(size_t)row * CLSS + col] = v;
                else                op[(size_t)row * CLSS + col] = v;
            }
        }
    }
}

// ---------------- launch ----------------
extern "C" void kernel_launch(void* const* d_in, const int* in_sizes, int n_in,
                              void* d_out, int out_size, void* d_ws, size_t ws_size,
                              hipStream_t stream) {
    const float* x_user    = (const float*)d_in[0];
    const float* x_product = (const float*)d_in[1];
    const int*   ei        = (const int*)d_in[2];
    const float* w_u1_l = (const float*)d_in[3];
    const float* b_u1   = (const float*)d_in[4];
    const float* w_u1_r = (const float*)d_in[5];
    const float* w_p1_l = (const float*)d_in[6];
    const float* b_p1   = (const float*)d_in[7];
    const float* w_p1_r = (const float*)d_in[8];
    const float* w_u2_l = (const float*)d_in[9];
    const float* b_u2   = (const float*)d_in[10];
    const float* w_u2_r = (const float*)d_in[11];
    const float* w_p2_l = (const float*)d_in[12];
    const float* b_p2   = (const float*)d_in[13];
    const float* w_p2_r = (const float*)d_in[14];

    float* out_u = (float*)d_out;
    float* out_p = out_u + (size_t)Nn * CLSS;

    char* w = (char*)d_ws;
    int* bin_cnt  = (int*)w; w += (size_t)2 * NBIN * 4;
    int* bin_base = (int*)w; w += (size_t)2 * NBIN * 4;
    int* off  = (int*)w;  w += (size_t)2 * Nn * 4;
    int* cnt  = (int*)w;  w += (size_t)2 * Nn * 4;
    int* src_p = (int*)w; w += (size_t)Ee * 4;
    int* src_u = (int*)w; w += (size_t)Ee * 4;
    uint_t* ent_p = (uint_t*)w; w += (size_t)NBIN * BCAP * 4;
    uint_t* ent_u = (uint_t*)w; w += (size_t)NBIN * BCAP * 4;
    uintptr_t a = (uintptr_t)w; a = (a + 255) & ~(uintptr_t)255; w = (char*)a;
    us_t* xbu  = (us_t*)w; w += (size_t)Nn * FIN * 2;
    us_t* xbp  = (us_t*)w; w += (size_t)Nn * FIN * 2;
    uint_t* xf8u = (uint_t*)w; w += (size_t)Nn * FIN;     // fp8, 4 per uint
    uint_t* xf8p = (uint_t*)w; w += (size_t)Nn * FIN;
    us_t* h_u  = (us_t*)w; w += (size_t)Nn * HIDD * 2;
    us_t* h_p  = (us_t*)w; w += (size_t)Nn * HIDD * 2;
    us_t* mean_u = (us_t*)w; w += (size_t)Nn * FIN * 2;
    us_t* mean_p = (us_t*)w; w += (size_t)Nn * FIN * 2;
    us_t* tbuf_u = (us_t*)w; w += (size_t)Nn * CLSS * 2;
    us_t* tbuf_p = (us_t*)w; w += (size_t)Nn * CLSS * 2;
    us_t* wb_u1l = (us_t*)w; w += (size_t)HIDD * FIN * 2;
    us_t* wb_u1r = (us_t*)w; w += (size_t)HIDD * FIN * 2;
    us_t* wb_p1l = (us_t*)w; w += (size_t)HIDD * FIN * 2;
    us_t* wb_p1r = (us_t*)w; w += (size_t)HIDD * FIN * 2;
    us_t* wb_u2l = (us_t*)w; w += (size_t)CLSS * HIDD * 2;
    us_t* wb_u2r = (us_t*)w; w += (size_t)CLSS * HIDD * 2;
    us_t* wb_p2l = (us_t*)w; w += (size_t)CLSS * HIDD * 2;
    us_t* wb_p2r = (us_t*)w; w += (size_t)CLSS * HIDD * 2;

    // conversions + bin_cnt zero
    {
        int n4 = (Nn * FIN) / 4;
        int blocks = (n4 + 255) / 256; if (blocks > 1024) blocks = 1024;
        dim3 g(blocks, 2);
        k_cvtx<<<g, 256, 0, stream>>>(x_user, x_product, xbu, xbp, xf8u, xf8p, n4);
    }
    k_cvtw<<<193, 256, 0, stream>>>(w_u1_l, w_u1_r, w_p1_l, w_p1_r,
                                    w_u2_l, w_u2_r, w_p2_l, w_p2_r,
                                    wb_u1l, wb_u1r, wb_p1l, wb_p1r,
                                    wb_u2l, wb_u2r, wb_p2l, wb_p2r, bin_cnt);

    // binned CSR build
    k_bin<<<NEB, 256, 0, stream>>>(ei, bin_cnt, ent_p, ent_u);
    k_binscan<<<1, 256, 0, stream>>>(bin_cnt, bin_base);
    dim3 gsc(NBIN, 2);
    k_scatter<<<gsc, 512, 0, stream>>>(ent_p, ent_u, bin_cnt, bin_base,
                                       off, cnt, src_p, src_u);

    // ---- layer 1 ----
    dim3 ga1((Nn + 15) / 16, 2);
    k_agg1<<<ga1, 256, 0, stream>>>((const uint2*)xf8u, (const uint2*)xf8p,
                                    off, cnt, src_p, src_u, mean_u, mean_p);
    dim3 g1((Nn + 63) / 64, HIDD / 128, 2);
    k_mm1<<<g1, 256, 0, stream>>>(mean_u, mean_p, xbu, xbp,
                                  wb_u1l, wb_u1r, wb_p1l, wb_p1r,
                                  b_u1, b_p1, h_u, h_p);

    // ---- layer 2 ----
    dim3 g2((Nn + 63) / 64, 1, 4);
    k_mm2<<<g2, 256, 0, stream>>>(h_u, h_p, wb_u2l, wb_u2r, wb_p2l, wb_p2r,
                                  b_u2, b_p2, tbuf_u, tbuf_p, out_u, out_p);
    dim3 ga2((Nn + 15) / 16, 2);
    k_agg2<<<ga2, 256, 0, stream>>>(tbuf_u, tbuf_p, off, cnt, src_p, src_u, out_u, out_p);
}